// Round 11
// baseline (1655.245 us; speedup 1.0000x reference)
//
#include <hip/hip_runtime.h>

// ---------------------------------------------------------------------------
// Transformer block, f32-faithful pre-gate pipeline via split-fp16 3-MFMA
// GEMMs; MoE gate/argmax in pure f32; experts in single fp16.
// GEMM: 128x128 tile, 4 waves, SINGLE 32KB LDS buffer + syncthreads drain
// (m97 structure) -> 4-5 blocks/CU; occupancy hides the drain (m114).
// MoE gather GEMMs use a device-built dense tile plan (<=36 m-tiles).
// wo/ff2/moe-down are K-split x2 into f32 partials + reduce kernel.
// Attention: V pre-transposed in QKV epilogue; Q frags in regs; 48KB LDS.
// ---------------------------------------------------------------------------

using f16   = _Float16;
using f16x4 = __attribute__((ext_vector_type(4))) _Float16;
using f16x8 = __attribute__((ext_vector_type(8))) _Float16;
using f32x4 = __attribute__((ext_vector_type(4))) float;

__device__ __forceinline__ void async16(void* l, const void* g) {
  __builtin_amdgcn_global_load_lds(
      (const __attribute__((address_space(1))) unsigned*)g,
      (__attribute__((address_space(3))) unsigned*)l, 16, 0, 0);
}

// ---------------- weight transpose f32[R][Cc] -> f16 (hi[,lo]) [Cc][R] ------
template <bool SPLITW>
__global__ __launch_bounds__(256) void transpose_k(
    const float* __restrict__ in, f16* __restrict__ oh, f16* __restrict__ ol,
    int R, int Cc) {
  const size_t bofs = (size_t)blockIdx.y * R * Cc;
  in += bofs; oh += bofs;
  if constexpr (SPLITW) ol += bofs;
  __shared__ float tile[32][33];
  const int nbx = Cc >> 5;
  const int bx = blockIdx.x % nbx, by = blockIdx.x / nbx;
  const int tx = threadIdx.x & 31, ty = threadIdx.x >> 5;
#pragma unroll
  for (int i = 0; i < 4; ++i) {
    int r = ty + i * 8;
    tile[r][tx] = in[(size_t)(by * 32 + r) * Cc + bx * 32 + tx];
  }
  __syncthreads();
#pragma unroll
  for (int i = 0; i < 4; ++i) {
    int oc = ty + i * 8;
    float v = tile[tx][oc];
    size_t o = (size_t)(bx * 32 + oc) * R + by * 32 + tx;
    f16 hi = (f16)v;
    oh[o] = hi;
    if constexpr (SPLITW) ol[o] = (f16)(v - (float)hi);
  }
}

// ---------------- LayerNorm f32 -> split f16 pair, row length 1024 ----------
__global__ __launch_bounds__(256) void ln_k(
    const float* __restrict__ x, const float* __restrict__ g,
    const float* __restrict__ b, f16* __restrict__ outh, f16* __restrict__ outl) {
  const int row = blockIdx.x;
  const float4 vv = ((const float4*)(x + (size_t)row * 1024))[threadIdx.x];
  float s = vv.x + vv.y + vv.z + vv.w;
  float sq = vv.x * vv.x + vv.y * vv.y + vv.z * vv.z + vv.w * vv.w;
#pragma unroll
  for (int mm = 32; mm; mm >>= 1) { s += __shfl_xor(s, mm); sq += __shfl_xor(sq, mm); }
  __shared__ float red[8];
  const int wv = threadIdx.x >> 6;
  if ((threadIdx.x & 63) == 0) { red[wv] = s; red[4 + wv] = sq; }
  __syncthreads();
  s = red[0] + red[1] + red[2] + red[3];
  sq = red[4] + red[5] + red[6] + red[7];
  const float mean = s * 0.0009765625f;
  const float rstd = rsqrtf(sq * 0.0009765625f - mean * mean + 1e-5f);
  const int c = threadIdx.x * 4;
  const float xs[4] = {vv.x, vv.y, vv.z, vv.w};
  f16x4 ovh, ovl;
#pragma unroll
  for (int i = 0; i < 4; ++i) {
    float val = (xs[i] - mean) * rstd * g[c + i] + b[c + i];
    f16 hi = (f16)val;
    ovh[i] = hi;
    ovl[i] = (f16)(val - (float)hi);
  }
  *(f16x4*)(outh + (size_t)row * 1024 + c) = ovh;
  *(f16x4*)(outl + (size_t)row * 1024 + c) = ovl;
}

// ---------------- gate: f32 LN + h@gate_w + argmax + routing ----------------
__global__ __launch_bounds__(256) void gate_k(
    const float* __restrict__ x, const float* __restrict__ g, const float* __restrict__ b,
    const float* __restrict__ gw, const float* __restrict__ gb,
    int* __restrict__ cnt, int* __restrict__ idxAll, int* __restrict__ eid) {
  const int t = blockIdx.x;
  const float4 vv = ((const float4*)(x + (size_t)t * 1024))[threadIdx.x];
  float s = vv.x + vv.y + vv.z + vv.w;
  float sq = vv.x * vv.x + vv.y * vv.y + vv.z * vv.z + vv.w * vv.w;
#pragma unroll
  for (int mm = 32; mm; mm >>= 1) { s += __shfl_xor(s, mm); sq += __shfl_xor(sq, mm); }
  __shared__ float red[8];
  __shared__ float redv[4][4];
  const int wv = threadIdx.x >> 6;
  if ((threadIdx.x & 63) == 0) { red[wv] = s; red[4 + wv] = sq; }
  __syncthreads();
  s = red[0] + red[1] + red[2] + red[3];
  sq = red[4] + red[5] + red[6] + red[7];
  const float mean = s * 0.0009765625f;
  const float rstd = rsqrtf(sq * 0.0009765625f - mean * mean + 1e-5f);
  const int c = threadIdx.x * 4;
  const float xs[4] = {vv.x, vv.y, vv.z, vv.w};
  float a0 = 0.f, a1 = 0.f, a2 = 0.f, a3 = 0.f;
#pragma unroll
  for (int i = 0; i < 4; ++i) {
    float ln = (xs[i] - mean) * rstd * g[c + i] + b[c + i];
    const float4 w4 = ((const float4*)gw)[c + i];
    a0 += ln * w4.x; a1 += ln * w4.y; a2 += ln * w4.z; a3 += ln * w4.w;
  }
#pragma unroll
  for (int mm = 32; mm; mm >>= 1) {
    a0 += __shfl_xor(a0, mm); a1 += __shfl_xor(a1, mm);
    a2 += __shfl_xor(a2, mm); a3 += __shfl_xor(a3, mm);
  }
  if ((threadIdx.x & 63) == 0) {
    redv[wv][0] = a0; redv[wv][1] = a1; redv[wv][2] = a2; redv[wv][3] = a3;
  }
  __syncthreads();
  if (threadIdx.x == 0) {
    float ge[4];
#pragma unroll
    for (int e = 0; e < 4; ++e)
      ge[e] = redv[0][e] + redv[1][e] + redv[2][e] + redv[3][e] + gb[e];
    int be = 0; float bvv = ge[0];
#pragma unroll
    for (int e = 1; e < 4; ++e) if (ge[e] > bvv) { bvv = ge[e]; be = e; }
    int pos = atomicAdd(&cnt[be], 1);
    idxAll[(be << 12) + pos] = t;
    eid[t] = be;
  }
}

__global__ void init_moe(int* cnt) { if (threadIdx.x < 4) cnt[threadIdx.x] = 0; }

// ---------------- plan: cnt[] -> dense m-tile descriptors (expert, m0) ------
#define MAXMT 36
__global__ void plan_k(const int* __restrict__ cnt, int* __restrict__ desc) {
  if (threadIdx.x == 0) {
    int t = 0;
    for (int e = 0; e < 4; ++e) {
      const int c = cnt[e];
      for (int m = 0; m < c; m += 128) desc[t++] = (e << 16) | (m >> 7);
    }
    for (; t < MAXMT; ++t) desc[t] = -1;
  }
}

// ---------------- reduce: out = res + p0 + p1 + bias (MOE: bias per expert) -
template <bool MOE>
__global__ __launch_bounds__(256) void reduce_k(
    const float* __restrict__ p0, const float* __restrict__ p1,
    const float* __restrict__ res, const float* __restrict__ bias,
    const int* __restrict__ eid, float* __restrict__ o) {
  const int row = blockIdx.x, t = threadIdx.x;
  const float* bp = MOE ? bias + (size_t)eid[row] * 1024 : bias;
  const float4 a = ((const float4*)(p0 + (size_t)row * 1024))[t];
  const float4 b = ((const float4*)(p1 + (size_t)row * 1024))[t];
  const float4 r = ((const float4*)(res + (size_t)row * 1024))[t];
  const float4 bb = ((const float4*)bp)[t];
  float4 o4;
  o4.x = r.x + a.x + b.x + bb.x;
  o4.y = r.y + a.y + b.y + bb.y;
  o4.z = r.z + a.z + b.z + bb.z;
  o4.w = r.w + a.w + b.w + bb.w;
  ((float4*)(o + (size_t)row * 1024))[t] = o4;
}

// ---------------- 128x128 fp16 MFMA GEMM, single-buffer m97 loop ------------
// A[M][K], Bt[N][K]. OUT: 0=f32, 1=split f16 pair, 2=single f16, 3=f32 partial
// (outf ks=0, outf2 ks=1). SPLIT: hi/lo interleaved along K (BK=32).
// QKV3: q/k written [buf][tok][1024]; v third written transposed
// v_t[(b*16+h)][d][tok]. GATHER: dense m-tile plan in desc[].
template <bool SPLIT, bool RELU, bool BIAS, bool RES, bool GATHER, int OUT,
          bool QKV3, bool KSPLIT>
__global__ __launch_bounds__(256, 4) void gemm_k(
    const f16* __restrict__ Ah, const f16* __restrict__ Al,
    const f16* __restrict__ Bh, const f16* __restrict__ Bl,
    float* __restrict__ outf, float* __restrict__ outf2,
    f16* __restrict__ outh, f16* __restrict__ outl,
    const float* __restrict__ bias, const float* __restrict__ res,
    const int* __restrict__ idxAll, const int* __restrict__ cntAll,
    const int* __restrict__ desc,
    int M, int N, int K) {
  const int NB = N >> 7;
  int m0, n0, ks = 0;
  int cnt = M;
  const int* idx = nullptr;
  if constexpr (GATHER) {
    int rem = blockIdx.x;
    if constexpr (KSPLIT) {
      const int half = (int)gridDim.x >> 1;
      ks = rem >= half; rem -= ks * half;
    }
    const int mt = rem / NB, nt = rem - mt * NB;
    const int d = desc[mt];
    if (d < 0) return;
    const int e = d >> 16;
    m0 = (d & 0xffff) << 7;
    n0 = nt << 7;
    cnt = cntAll[e];
    idx = idxAll + (e << 12);
    Bh += (size_t)e * N * K;
    if (BIAS) bias += (size_t)e * N;
  } else {
    int rem = blockIdx.x;
    const int ntile = (int)gridDim.x >> (KSPLIT ? 1 : 0);
    if constexpr (KSPLIT) { ks = rem >= ntile; rem -= ks * ntile; }
    const int q2 = ntile >> 3;                   // ntile % 8 == 0 for our shapes
    const int bid = (rem & 7) * q2 + (rem >> 3); // XCD-bijective
    m0 = (bid / NB) << 7; n0 = (bid % NB) << 7;
  }

  __shared__ __align__(16) char lds[32768];  // single buffer: A 16K | B 16K

  const int tid = threadIdx.x;
  const int wave = tid >> 6, lane = tid & 63;
  const int wr = (wave >> 1) << 6, wc = (wave & 1) << 6;
  const int srow = lane >> 3;
  const int lc = (lane & 7) ^ srow;            // logical chunk staged by lane
  const int kofs = (SPLIT ? (lc >> 1) : lc) << 4;

  const int kshift = (KSPLIT && ks) ? (K >> 1) : 0;

  // staging sources (per-thread, tile 0); hi/lo interleaved: even lc = hi
  const char* srcA[4];
  const char* srcB[4];
#pragma unroll
  for (int s = 0; s < 4; ++s) {
    const int tr = (wave * 4 + s) * 8 + srow;
    int gm = m0 + tr;
    if constexpr (GATHER) gm = idx[gm < cnt ? gm : cnt - 1];
    const f16* baseA = (SPLIT && (lc & 1)) ? Al : Ah;
    srcA[s] = (const char*)baseA + ((size_t)gm * K + kshift) * 2 + kofs;
    const f16* baseB = (SPLIT && (lc & 1)) ? Bl : Bh;
    srcB[s] = (const char*)baseB + ((size_t)(n0 + tr) * K + kshift) * 2 + kofs;
  }
  char* const ldsw = lds + wave * 4096;

  // ds_read byte offsets, loop-invariant
  const int s4 = lane >> 4, l7 = lane & 7, fr = lane & 15;
  int offAh[4], offAl[4], offBh[4], offBl[4];
#pragma unroll
  for (int i = 0; i < 4; ++i) {
    const int row = wr + i * 16 + fr;
    const int col = wc + i * 16 + fr;
    if constexpr (SPLIT) {
      offAh[i] = row * 128 + (((2 * s4) ^ l7) << 4);
      offAl[i] = row * 128 + (((2 * s4 + 1) ^ l7) << 4);
      offBh[i] = 16384 + col * 128 + (((2 * s4) ^ l7) << 4);
      offBl[i] = 16384 + col * 128 + (((2 * s4 + 1) ^ l7) << 4);
    } else {
      offAh[i] = row * 128 + ((s4 ^ l7) << 4);           // ks=0
      offAl[i] = row * 128 + (((4 + s4) ^ l7) << 4);     // ks=1
      offBh[i] = 16384 + col * 128 + ((s4 ^ l7) << 4);
      offBl[i] = 16384 + col * 128 + (((4 + s4) ^ l7) << 4);
    }
  }

  f32x4 acc[4][4] = {};

  constexpr int KSTEP = SPLIT ? 32 : 64;
  const int nt_ = (KSPLIT ? (K >> 1) : K) / KSTEP;

  for (int t = 0; t < nt_; ++t) {
    const size_t kb = (size_t)t * (KSTEP * 2);
#pragma unroll
    for (int s = 0; s < 4; ++s) {
      async16(ldsw + s * 1024, srcA[s] + kb);
      async16(ldsw + 16384 + s * 1024, srcB[s] + kb);
    }
    __syncthreads();   // drains vmcnt + barrier (m97 structure)

    f16x8 va[4], vb[4], va2[4], vb2[4];
#pragma unroll
    for (int i = 0; i < 4; ++i) {
      va[i]  = *(const f16x8*)(lds + offAh[i]);
      va2[i] = *(const f16x8*)(lds + offAl[i]);
      vb[i]  = *(const f16x8*)(lds + offBh[i]);
      vb2[i] = *(const f16x8*)(lds + offBl[i]);
    }
    __builtin_amdgcn_s_setprio(1);
#pragma unroll
    for (int i = 0; i < 4; ++i)
#pragma unroll
      for (int j = 0; j < 4; ++j) {
        if constexpr (SPLIT) {
          acc[i][j] = __builtin_amdgcn_mfma_f32_16x16x32_f16(va[i],  vb[j],  acc[i][j], 0, 0, 0);
          acc[i][j] = __builtin_amdgcn_mfma_f32_16x16x32_f16(va2[i], vb[j],  acc[i][j], 0, 0, 0);
          acc[i][j] = __builtin_amdgcn_mfma_f32_16x16x32_f16(va[i],  vb2[j], acc[i][j], 0, 0, 0);
        } else {
          acc[i][j] = __builtin_amdgcn_mfma_f32_16x16x32_f16(va[i],  vb[j],  acc[i][j], 0, 0, 0);
          acc[i][j] = __builtin_amdgcn_mfma_f32_16x16x32_f16(va2[i], vb2[j], acc[i][j], 0, 0, 0);
        }
      }
    __builtin_amdgcn_s_setprio(0);
    __syncthreads();   // protect buffer before next stage
  }

  const int cl = lane & 15, rg = lane >> 4;
  float* const po = (OUT == 3) ? (ks ? outf2 : outf) : outf;
#pragma unroll
  for (int i = 0; i < 4; ++i) {
#pragma unroll
    for (int r = 0; r < 4; ++r) {
      const int mloc = m0 + wr + i * 16 + rg * 4 + r;
      if (GATHER && mloc >= cnt) continue;
      const int orow = GATHER ? idx[mloc] : mloc;
#pragma unroll
      for (int j = 0; j < 4; ++j) {
        const int col = n0 + wc + j * 16 + cl;
        float v2 = acc[i][j][r];
        if (BIAS) v2 += bias[col];
        if (RELU) v2 = v2 > 0.f ? v2 : 0.f;
        if (RES) v2 += res[(size_t)orow * N + col];
        size_t oidx;
        if constexpr (QKV3) {
          if (col < 2048) {
            oidx = ((size_t)(col >> 10) * M + orow) * 1024 + (col & 1023);
          } else {
            const int c = col - 2048;  // head*64 + d
            oidx = (size_t)2 * M * 1024 +
                   (((size_t)(orow >> 10) * 16 + (c >> 6)) * 64 + (c & 63)) * 1024 +
                   (orow & 1023);
          }
        } else {
          oidx = (size_t)orow * N + col;
        }
        if constexpr (OUT == 0 || OUT == 3) {
          po[oidx] = v2;
        } else if constexpr (OUT == 1) {
          f16 hi = (f16)v2;
          outh[oidx] = hi;
          outl[oidx] = (f16)(v2 - (float)hi);
        } else {
          outh[oidx] = (f16)v2;
        }
      }
    }
  }
}

// ---------------- flash attention, causal, D=64, split-fp16 -----------------
__global__ __launch_bounds__(256, 3) void attn_k(
    const f16* __restrict__ qh, const f16* __restrict__ ql,
    const f16* __restrict__ kh, const f16* __restrict__ kl,
    const f16* __restrict__ vth, const f16* __restrict__ vtl,
    f16* __restrict__ oh, f16* __restrict__ ol) {
  const int qt = 15 - (blockIdx.x & 15), hd = (blockIdx.x >> 4) & 15, bb = blockIdx.x >> 8;
  const int tid = threadIdx.x, wave = tid >> 6, lane = tid & 63;
  __shared__ __align__(16) char QPs[16384], Ks[16384], Vs[16384];
  const int swz = (((lane & 7) ^ ((lane >> 3) & 7)) << 4);
  const size_t tok0 = (size_t)bb * 1024;
  const int hoff = hd * 64;
  const size_t vbase = ((size_t)(bb * 16 + hd) * 64) * 1024;  // v_t rows
  const float L2E = 1.44269504089f;

#pragma unroll
  for (int r = 0; r < 2; ++r) {
    const int chunk = wave * 2 + r;
    const int row = chunk * 8 + (lane >> 3);
    const size_t byte = (((tok0 + qt * 64 + row) * 1024 + hoff) << 1) + swz;
    async16(QPs + chunk * 1024, (const char*)qh + byte);
    async16(QPs + 8192 + chunk * 1024, (const char*)ql + byte);
  }
  __syncthreads();
  f16x8 qr_h[2], qr_l[2];
#pragma unroll
  for (int ks = 0; ks < 2; ++ks) {
    const int qrow = wave * 16 + (lane & 15);
    const int qoff = qrow * 128 + ((((ks << 2) + (lane >> 4)) ^ (qrow & 7)) << 4);
    qr_h[ks] = *(const f16x8*)(QPs + qoff);
    qr_l[ks] = *(const f16x8*)(QPs + 8192 + qoff);
  }

  f32x4 oacc[4] = {};
  float mrun[4] = {-1e30f, -1e30f, -1e30f, -1e30f};
  float lrun[4] = {};

  for (int kt = 0; kt <= qt; ++kt) {
    __syncthreads();
#pragma unroll
    for (int r = 0; r < 2; ++r) {
      const int chunk = wave * 2 + r;
      const int row = chunk * 8 + (lane >> 3);
      const size_t kbyte = (((tok0 + kt * 64 + row) * 1024 + hoff) << 1) + swz;
      async16(Ks + chunk * 1024, (const char*)kh + kbyte);
      async16(Ks + 8192 + chunk * 1024, (const char*)kl + kbyte);
      const size_t vbyte = (((vbase + (size_t)row * 1024) + kt * 64) << 1) + swz;
      async16(Vs + chunk * 1024, (const char*)vth + vbyte);
      async16(Vs + 8192 + chunk * 1024, (const char*)vtl + vbyte);
    }
    __syncthreads();

    f32x4 s[4] = {};
#pragma unroll
    for (int ks = 0; ks < 2; ++ks) {
#pragma unroll
      for (int j = 0; j < 4; ++j) {
        const int col = j * 16 + (lane & 15);
        const int koff = col * 128 + ((((ks << 2) + (lane >> 4)) ^ (col & 7)) << 4);
        f16x8 b_h = *(const f16x8*)(Ks + koff);
        f16x8 b_l = *(const f16x8*)(Ks + 8192 + koff);
        s[j] = __builtin_amdgcn_mfma_f32_16x16x32_f16(qr_h[ks], b_h, s[j], 0, 0, 0);
        s[j] = __builtin_amdgcn_mfma_f32_16x16x32_f16(qr_l[ks], b_h, s[j], 0, 0, 0);
        s[j] = __builtin_amdgcn_mfma_f32_16x16x32_f16(qr_h[ks], b_l, s[j], 0, 0, 0);
      }
    }

    const bool diag = (kt == qt);
    float pmax[4] = {-1e30f, -1e30f, -1e30f, -1e30f};
#pragma unroll
    for (int j = 0; j < 4; ++j)
#pragma unroll
      for (int r = 0; r < 4; ++r) {
        float sv = s[j][r] * 0.125f;
        if (diag) {
          const int qloc = wave * 16 + (lane >> 4) * 4 + r;
          const int kvl = j * 16 + (lane & 15);
          if (kvl > qloc) sv = -1e30f;
        }
        s[j][r] = sv;
        pmax[r] = fmaxf(pmax[r], sv);
      }
    char* pbh = QPs + wave * 2048;
    char* pbl = QPs + 8192 + wave * 2048;
#pragma unroll
    for (int r = 0; r < 4; ++r) {
#pragma unroll
      for (int mm = 1; mm < 16; mm <<= 1)
        pmax[r] = fmaxf(pmax[r], __shfl_xor(pmax[r], mm, 16));
      const float mnew = fmaxf(mrun[r], pmax[r]);
      const float al = exp2f((mrun[r] - mnew) * L2E);
      mrun[r] = mnew;
      lrun[r] *= al;
      oacc[0][r] *= al; oacc[1][r] *= al; oacc[2][r] *= al; oacc[3][r] *= al;
    }

    float psum[4] = {};
#pragma unroll
    for (int j = 0; j < 4; ++j)
#pragma unroll
      for (int r = 0; r < 4; ++r) {
        const float p = exp2f((s[j][r] - mrun[r]) * L2E);
        psum[r] += p;
        const int lr = (lane >> 4) * 4 + r;
        const int kvl = j * 16 + (lane & 15);
        const int poff = lr * 128 + ((kvl * 2) ^ ((lr & 7) << 4));
        f16 ph = (f16)p;
        *(f16*)(pbh + poff) = ph;
        *(f16*)(pbl + poff) = (f16)(p - (float)ph);
      }
#pragma unroll
    for (int r = 0; r < 4; ++r) {
#pragma unroll
      for (int mm = 1; mm < 16; mm <<= 1)
        psum[r] += __shfl_xor(psum[r], mm, 16);
      lrun[r] += psum[r];
    }

#pragma unroll
    for (int ks = 0; ks < 2; ++ks) {
      const int prow = lane & 15;
      const int poff = prow * 128 + ((((ks << 2) + (lane >> 4)) ^ (prow & 7)) << 4);
      f16x8 a_h = *(const f16x8*)(pbh + poff);
      f16x8 a_l = *(const f16x8*)(pbl + poff);
#pragma unroll
      for (int jd = 0; jd < 4; ++jd) {
        const int col = jd * 16 + (lane & 15);
        const int voff = col * 128 + ((((ks << 2) + (lane >> 4)) ^ (col & 7)) << 4);
        f16x8 b_h = *(const f16x8*)(Vs + voff);
        f16x8 b_l = *(const f16x8*)(Vs + 8192 + voff);
        oacc[jd] = __builtin_amdgcn_mfma_f32_16x16x32_f16(a_h, b_h, oacc[jd], 0, 0, 0);
        oacc[jd] = __builtin_amdgcn_mfma_f32_16x16x32_f16(a_l, b_h, oacc[jd], 0, 0, 0);
        oacc[jd] = __builtin_amdgcn_mfma_f32_16x16x32_f16(a_h, b_l, oacc[jd], 0, 0, 0);
      }
    }
  }

#pragma unroll
  for (int r = 0; r < 4; ++r) {
    const float inv = 1.0f / lrun[r];
    const size_t trow = tok0 + qt * 64 + wave * 16 + (lane >> 4) * 4 + r;
#pragma unroll
    for (int jd = 0; jd < 4; ++jd) {
      const int col = hoff + jd * 16 + (lane & 15);
      const float val = oacc[jd][r] * inv;
      const f16 hi = (f16)val;
      oh[trow * 1024 + col] = hi;
      ol[trow * 1024 + col] = (f16)(val - (float)hi);
    }
  }
}

// ---------------------------------------------------------------------------
extern "C" void kernel_launch(void* const* d_in, const int* in_sizes, int n_in,
                              void* d_out, int out_size, void* d_ws, size_t ws_size,
                              hipStream_t stream) {
  const float* x0   = (const float*)d_in[0];
  const float* wq   = (const float*)d_in[1];
  const float* wk   = (const float*)d_in[2];
  const float* wv   = (const float*)d_in[3];
  const float* wo   = (const float*)d_in[4];
  const float* bo   = (const float*)d_in[5];
  const float* ffw1 = (const float*)d_in[6];
  const float* ffb1 = (const float*)d_in[7];
  const float* ffw2 = (const float*)d_in[8];
  const float* ffb2 = (const float*)d_in[9];
  const float* ew1  = (const float*)d_in[10];
  const float* eb1  = (const float*)d_in[11];
  const float* ew2  = (const float*)d_in[12];
  const float* eb2  = (const float*)d_in[13];
  const float* gw   = (const float*)d_in[14];
  const float* gb   = (const float*)d_in[15];
  const float* l1g  = (const float*)d_in[16];
  const float* l1b  = (const float*)d_in[17];
  const float* l2g  = (const float*)d_in[18];
  const float* l2b  = (const float*)d_in[19];
  const float* l3g  = (const float*)d_in[20];
  const float* l3b  = (const float*)d_in[21];
  float* out = (float*)d_out;

  char* w = (char*)d_ws;
  const size_t M1 = (size_t)1024 * 1024;       // elems of a 1024x1024 f16
  const size_t A1 = (size_t)4096 * 1024 * 2;   // 8MB  (f16 4096x1024)
  const size_t W4 = (size_t)1024 * 4096 * 2;   // 8MB  (f16 1024x4096)
  f16* wqkvh = (f16*)w; w += 3 * M1 * 2;       // 6MB  [3072][1024] hi
  f16* wqkvl = (f16*)w; w += 3 * M1 * 2;       // 6MB  lo
  f16* woh = (f16*)w; w += M1 * 2;             // 2MB
  f16* wol = (f16*)w; w += M1 * 2;             // 2MB
  f16* f1h = (f16*)w; w += W4;  f16* f1l = (f16*)w; w += W4;
  f16* f2h = (f16*)w; w += W4;  f16* f2l = (f16*)w; w += W4;
  f16* e1t = (f16*)w; w += 4 * W4;
  f16* e2t = (f16*)w; w += 4 * W4;
  f16* hh  = (f16*)w; w += A1;  f16* hl  = (f16*)w; w += A1;
  f16* qkv_h = (f16*)w; w += 3 * A1;           // q,k row-major; v transposed
  f16* qkv_l = (f16*)w; w += 3 * A1;
  f16* o_h = (f16*)w; w += A1;  f16* o_l = (f16*)w; w += A1;
  float* x1 = (float*)w; w += (size_t)4096 * 1024 * 4;
  int* cnt = (int*)w; w += 256;
  int* idx = (int*)w; w += (size_t)4 * 4096 * 4;
  int* eid = (int*)w; w += (size_t)4096 * 4;
  int* desc = (int*)w; w += 256;
  // aliases over sequentially-dead regions:
  f16* hid_h = qkv_h;                                     // FFN hidden hi (32MB)
  f16* hid_l = (f16*)((char*)qkv_h + (((size_t)32) << 20)); // FFN hidden lo (32MB)
  f16* ffh   = qkv_h;                                     // MoE hidden (32MB)
  // K-split partial buffers (16MB each), all over dead regions at use time:
  float* pW0 = (float*)hh;      // wo: ln1-out dead after qkv
  float* pW1 = (float*)qkv_h;   // wo: q/k/v dead after attn
  float* pF0 = (float*)wqkvh;   // ff2: qkv+wo weights dead
  float* pF1 = (float*)hh;      // ff2: ln2-out dead after ff1
  float* pM0 = (float*)((char*)qkv_l + (((size_t)8) << 20));  // moe: free tail
  float* pM1 = (float*)o_h;     // moe: attn-out dead after wo

  // ---- weights -> f16 (split for pre-gate, single for experts) ----
  transpose_k<true><<<1024, 256, 0, stream>>>(wq, wqkvh, wqkvl, 1024, 1024);
  transpose_k<true><<<1024, 256, 0, stream>>>(wk, wqkvh + M1, wqkvl + M1, 1024, 1024);
  transpose_k<true><<<1024, 256, 0, stream>>>(wv, wqkvh + 2 * M1, wqkvl + 2 * M1, 1024, 1024);
  transpose_k<true><<<1024, 256, 0, stream>>>(wo, woh, wol, 1024, 1024);
  transpose_k<true><<<4096, 256, 0, stream>>>(ffw1, f1h, f1l, 1024, 4096);
  transpose_k<true><<<4096, 256, 0, stream>>>(ffw2, f2h, f2l, 4096, 1024);
  transpose_k<false><<<dim3(4096, 4), 256, 0, stream>>>(ew1, e1t, nullptr, 1024, 4096);
  transpose_k<false><<<dim3(4096, 4), 256, 0, stream>>>(ew2, e2t, nullptr, 4096, 1024);

  const size_t TOK = (size_t)4096 * 1024;
  // ---- attention ----
  ln_k<<<4096, 256, 0, stream>>>(x0, l1g, l1b, hh, hl);
  gemm_k<true, false, false, false, false, 1, true, false><<<768, 256, 0, stream>>>(
      hh, hl, wqkvh, wqkvl, nullptr, nullptr, qkv_h, qkv_l,
      nullptr, nullptr, nullptr, nullptr, nullptr, 4096, 3072, 1024);
  attn_k<<<1024, 256, 0, stream>>>(qkv_h, qkv_l, qkv_h + TOK, qkv_l + TOK,
                                   qkv_h + 2 * TOK, qkv_l + 2 * TOK, o_h, o_l);
  gemm_k<true, false, false, false, false, 3, false, true><<<512, 256, 0, stream>>>(
      o_h, o_l, woh, wol, pW0, pW1, nullptr, nullptr,
      nullptr, nullptr, nullptr, nullptr, nullptr, 4096, 1024, 1024);
  reduce_k<false><<<4096, 256, 0, stream>>>(pW0, pW1, x0, bo, nullptr, x1);

  // ---- dense FFN ----
  ln_k<<<4096, 256, 0, stream>>>(x1, l2g, l2b, hh, hl);
  gemm_k<true, true, true, false, false, 1, false, false><<<1024, 256, 0, stream>>>(
      hh, hl, f1h, f1l, nullptr, nullptr, hid_h, hid_l,
      ffb1, nullptr, nullptr, nullptr, nullptr, 4096, 4096, 1024);
  gemm_k<true, false, false, false, false, 3, false, true><<<512, 256, 0, stream>>>(
      hid_h, hid_l, f2h, f2l, pF0, pF1, nullptr, nullptr,
      nullptr, nullptr, nullptr, nullptr, nullptr, 4096, 1024, 4096);
  reduce_k<false><<<4096, 256, 0, stream>>>(pF0, pF1, x1, ffb2, nullptr, out);

  // ---- MoE (top-1 routed; gate in pure f32; dense tile plan) ----
  ln_k<<<4096, 256, 0, stream>>>(out, l3g, l3b, hh, hl);
  init_moe<<<1, 64, 0, stream>>>(cnt);
  gate_k<<<4096, 256, 0, stream>>>(out, l3g, l3b, gw, gb, cnt, idx, eid);
  plan_k<<<1, 64, 0, stream>>>(cnt, desc);
  gemm_k<false, true, true, false, true, 2, false, false><<<MAXMT * 32, 256, 0, stream>>>(
      hh, nullptr, e1t, nullptr, nullptr, nullptr, ffh, nullptr,
      eb1, nullptr, idx, cnt, desc, 4096, 4096, 1024);
  gemm_k<false, false, false, false, true, 3, false, true><<<2 * MAXMT * 8, 256, 0, stream>>>(
      ffh, nullptr, e2t, nullptr, pM0, pM1, nullptr, nullptr,
      nullptr, nullptr, idx, cnt, desc, 4096, 1024, 4096);
  reduce_k<true><<<4096, 256, 0, stream>>>(pM0, pM1, out, eb2, eid, out);
}

// Round 12
// 730.872 us; speedup vs baseline: 2.2648x; 2.2648x over previous
//
#include <hip/hip_runtime.h>

// ---------------------------------------------------------------------------
// Transformer block, f32-faithful pre-gate pipeline via split-fp16 3-MFMA
// GEMMs; MoE gate/argmax in pure f32; experts in single fp16.
// GEMM (m97-clone geometry): 128x128 tile, 4 waves, BK=64, SINGLE-buffer LDS
// ([A_hi|A_lo|B_hi|B_lo] regions, each gload_lds single-pointer), syncthreads
// drain; split 64KB -> 2 blocks/CU, non-split 32KB -> 3 blocks/CU (m114
// overlap hides the drain). XCD swizzle; dense MoE tile plan; K-split x2 for
// wo/ff2/moe-down into f32 partials + reduce.
// Attention: V pre-transposed in QKV epilogue; Q frags in regs; 48KB LDS.
// ---------------------------------------------------------------------------

using f16   = _Float16;
using f16x4 = __attribute__((ext_vector_type(4))) _Float16;
using f16x8 = __attribute__((ext_vector_type(8))) _Float16;
using f32x4 = __attribute__((ext_vector_type(4))) float;

__device__ __forceinline__ void async16(void* l, const void* g) {
  __builtin_amdgcn_global_load_lds(
      (const __attribute__((address_space(1))) unsigned*)g,
      (__attribute__((address_space(3))) unsigned*)l, 16, 0, 0);
}

// ---------------- weight transpose f32[R][Cc] -> f16 (hi[,lo]) [Cc][R] ------
template <bool SPLITW>
__global__ __launch_bounds__(256) void transpose_k(
    const float* __restrict__ in, f16* __restrict__ oh, f16* __restrict__ ol,
    int R, int Cc) {
  const size_t bofs = (size_t)blockIdx.y * R * Cc;
  in += bofs; oh += bofs;
  if constexpr (SPLITW) ol += bofs;
  __shared__ float tile[32][33];
  const int nbx = Cc >> 5;
  const int bx = blockIdx.x % nbx, by = blockIdx.x / nbx;
  const int tx = threadIdx.x & 31, ty = threadIdx.x >> 5;
#pragma unroll
  for (int i = 0; i < 4; ++i) {
    int r = ty + i * 8;
    tile[r][tx] = in[(size_t)(by * 32 + r) * Cc + bx * 32 + tx];
  }
  __syncthreads();
#pragma unroll
  for (int i = 0; i < 4; ++i) {
    int oc = ty + i * 8;
    float v = tile[tx][oc];
    size_t o = (size_t)(bx * 32 + oc) * R + by * 32 + tx;
    f16 hi = (f16)v;
    oh[o] = hi;
    if constexpr (SPLITW) ol[o] = (f16)(v - (float)hi);
  }
}

// ---------------- LayerNorm f32 -> split f16 pair, row length 1024 ----------
__global__ __launch_bounds__(256) void ln_k(
    const float* __restrict__ x, const float* __restrict__ g,
    const float* __restrict__ b, f16* __restrict__ outh, f16* __restrict__ outl) {
  const int row = blockIdx.x;
  const float4 vv = ((const float4*)(x + (size_t)row * 1024))[threadIdx.x];
  float s = vv.x + vv.y + vv.z + vv.w;
  float sq = vv.x * vv.x + vv.y * vv.y + vv.z * vv.z + vv.w * vv.w;
#pragma unroll
  for (int mm = 32; mm; mm >>= 1) { s += __shfl_xor(s, mm); sq += __shfl_xor(sq, mm); }
  __shared__ float red[8];
  const int wv = threadIdx.x >> 6;
  if ((threadIdx.x & 63) == 0) { red[wv] = s; red[4 + wv] = sq; }
  __syncthreads();
  s = red[0] + red[1] + red[2] + red[3];
  sq = red[4] + red[5] + red[6] + red[7];
  const float mean = s * 0.0009765625f;
  const float rstd = rsqrtf(sq * 0.0009765625f - mean * mean + 1e-5f);
  const int c = threadIdx.x * 4;
  const float xs[4] = {vv.x, vv.y, vv.z, vv.w};
  f16x4 ovh, ovl;
#pragma unroll
  for (int i = 0; i < 4; ++i) {
    float val = (xs[i] - mean) * rstd * g[c + i] + b[c + i];
    f16 hi = (f16)val;
    ovh[i] = hi;
    ovl[i] = (f16)(val - (float)hi);
  }
  *(f16x4*)(outh + (size_t)row * 1024 + c) = ovh;
  *(f16x4*)(outl + (size_t)row * 1024 + c) = ovl;
}

// ---------------- gate: f32 LN + h@gate_w + argmax + routing ----------------
__global__ __launch_bounds__(256) void gate_k(
    const float* __restrict__ x, const float* __restrict__ g, const float* __restrict__ b,
    const float* __restrict__ gw, const float* __restrict__ gb,
    int* __restrict__ cnt, int* __restrict__ idxAll, int* __restrict__ eid) {
  const int t = blockIdx.x;
  const float4 vv = ((const float4*)(x + (size_t)t * 1024))[threadIdx.x];
  float s = vv.x + vv.y + vv.z + vv.w;
  float sq = vv.x * vv.x + vv.y * vv.y + vv.z * vv.z + vv.w * vv.w;
#pragma unroll
  for (int mm = 32; mm; mm >>= 1) { s += __shfl_xor(s, mm); sq += __shfl_xor(sq, mm); }
  __shared__ float red[8];
  __shared__ float redv[4][4];
  const int wv = threadIdx.x >> 6;
  if ((threadIdx.x & 63) == 0) { red[wv] = s; red[4 + wv] = sq; }
  __syncthreads();
  s = red[0] + red[1] + red[2] + red[3];
  sq = red[4] + red[5] + red[6] + red[7];
  const float mean = s * 0.0009765625f;
  const float rstd = rsqrtf(sq * 0.0009765625f - mean * mean + 1e-5f);
  const int c = threadIdx.x * 4;
  const float xs[4] = {vv.x, vv.y, vv.z, vv.w};
  float a0 = 0.f, a1 = 0.f, a2 = 0.f, a3 = 0.f;
#pragma unroll
  for (int i = 0; i < 4; ++i) {
    float ln = (xs[i] - mean) * rstd * g[c + i] + b[c + i];
    const float4 w4 = ((const float4*)gw)[c + i];
    a0 += ln * w4.x; a1 += ln * w4.y; a2 += ln * w4.z; a3 += ln * w4.w;
  }
#pragma unroll
  for (int mm = 32; mm; mm >>= 1) {
    a0 += __shfl_xor(a0, mm); a1 += __shfl_xor(a1, mm);
    a2 += __shfl_xor(a2, mm); a3 += __shfl_xor(a3, mm);
  }
  if ((threadIdx.x & 63) == 0) {
    redv[wv][0] = a0; redv[wv][1] = a1; redv[wv][2] = a2; redv[wv][3] = a3;
  }
  __syncthreads();
  if (threadIdx.x == 0) {
    float ge[4];
#pragma unroll
    for (int e = 0; e < 4; ++e)
      ge[e] = redv[0][e] + redv[1][e] + redv[2][e] + redv[3][e] + gb[e];
    int be = 0; float bvv = ge[0];
#pragma unroll
    for (int e = 1; e < 4; ++e) if (ge[e] > bvv) { bvv = ge[e]; be = e; }
    int pos = atomicAdd(&cnt[be], 1);
    idxAll[(be << 12) + pos] = t;
    eid[t] = be;
  }
}

__global__ void init_moe(int* cnt) { if (threadIdx.x < 4) cnt[threadIdx.x] = 0; }

// ---------------- plan: cnt[] -> dense m-tile descriptors (expert, m0) ------
#define MAXMT 36
__global__ void plan_k(const int* __restrict__ cnt, int* __restrict__ desc) {
  if (threadIdx.x == 0) {
    int t = 0;
    for (int e = 0; e < 4; ++e) {
      const int c = cnt[e];
      for (int m = 0; m < c; m += 128) desc[t++] = (e << 16) | (m >> 7);
    }
    for (; t < MAXMT; ++t) desc[t] = -1;
  }
}

// ---------------- reduce: out = res + p0 + p1 + bias (MOE: bias per expert) -
template <bool MOE>
__global__ __launch_bounds__(256) void reduce_k(
    const float* __restrict__ p0, const float* __restrict__ p1,
    const float* __restrict__ res, const float* __restrict__ bias,
    const int* __restrict__ eid, float* __restrict__ o) {
  const int row = blockIdx.x, t = threadIdx.x;
  const float* bp = MOE ? bias + (size_t)eid[row] * 1024 : bias;
  const float4 a = ((const float4*)(p0 + (size_t)row * 1024))[t];
  const float4 b = ((const float4*)(p1 + (size_t)row * 1024))[t];
  const float4 r = ((const float4*)(res + (size_t)row * 1024))[t];
  const float4 bb = ((const float4*)bp)[t];
  float4 o4;
  o4.x = r.x + a.x + b.x + bb.x;
  o4.y = r.y + a.y + b.y + bb.y;
  o4.z = r.z + a.z + b.z + bb.z;
  o4.w = r.w + a.w + b.w + bb.w;
  ((float4*)(o + (size_t)row * 1024))[t] = o4;
}

// ---------------- 128x128 fp16 MFMA GEMM, BK=64, single-buffer (m97) --------
// A[M][K], Bt[N][K]. OUT: 0=f32, 1=split f16 pair, 2=single f16, 3=f32 partial
// (outf ks=0, outf2 ks=1). SPLIT: LDS regions [A_hi|A_lo|B_hi|B_lo] 16KB each.
// QKV3: q/k written [buf][tok][1024]; v third written transposed
// v_t[(b*16+h)][d][tok]. GATHER: dense m-tile plan in desc[].
template <bool SPLIT, bool RELU, bool BIAS, bool RES, bool GATHER, int OUT,
          bool QKV3, bool KSPLIT>
__global__ __launch_bounds__(256, SPLIT ? 2 : 3) void gemm_k(
    const f16* __restrict__ Ah, const f16* __restrict__ Al,
    const f16* __restrict__ Bh, const f16* __restrict__ Bl,
    float* __restrict__ outf, float* __restrict__ outf2,
    f16* __restrict__ outh, f16* __restrict__ outl,
    const float* __restrict__ bias, const float* __restrict__ res,
    const int* __restrict__ idxAll, const int* __restrict__ cntAll,
    const int* __restrict__ desc,
    int M, int N, int K) {
  const int NB = N >> 7;
  int m0, n0, ks = 0;
  int cnt = M;
  const int* idx = nullptr;
  if constexpr (GATHER) {
    int rem = blockIdx.x;
    if constexpr (KSPLIT) {
      const int half = (int)gridDim.x >> 1;
      ks = rem >= half; rem -= ks * half;
    }
    const int mt = rem / NB, nt = rem - mt * NB;
    const int d = desc[mt];
    if (d < 0) return;
    const int e = d >> 16;
    m0 = (d & 0xffff) << 7;
    n0 = nt << 7;
    cnt = cntAll[e];
    idx = idxAll + (e << 12);
    Bh += (size_t)e * N * K;
    if constexpr (SPLIT) Bl += (size_t)e * N * K;
    if (BIAS) bias += (size_t)e * N;
  } else {
    int rem = blockIdx.x;
    const int ntile = (int)gridDim.x >> (KSPLIT ? 1 : 0);
    if constexpr (KSPLIT) { ks = rem >= ntile; rem -= ks * ntile; }
    const int q2 = ntile >> 3;                   // ntile % 8 == 0 for our shapes
    const int bid = (rem & 7) * q2 + (rem >> 3); // XCD-bijective
    m0 = (bid / NB) << 7; n0 = (bid % NB) << 7;
  }

  // single buffer: [A_hi 16K][A_lo 16K if SPLIT][B_hi 16K][B_lo 16K if SPLIT]
  constexpr int RB = SPLIT ? 32768 : 16384;
  __shared__ __align__(16) char lds[SPLIT ? 65536 : 32768];

  const int tid = threadIdx.x;
  const int wave = tid >> 6, lane = tid & 63;
  const int wr = (wave >> 1) << 6, wc = (wave & 1) << 6;
  const int srow = lane >> 3;
  const int lc = (lane & 7) ^ srow;            // pre-swizzled chunk
  const int kofs = lc << 4;                    // 16B chunk within 128B row-seg

  const int kshift = (KSPLIT && ks) ? (K >> 1) : 0;

  // staging sources: each wave stages rows wave*32 .. wave*32+31 per region
  const char* sAh[4];
  const char* sAl[4];
  const char* sBh[4];
  const char* sBl[4];
#pragma unroll
  for (int s = 0; s < 4; ++s) {
    const int tr = (wave * 4 + s) * 8 + srow;
    int gm = m0 + tr;
    if constexpr (GATHER) gm = idx[gm < cnt ? gm : cnt - 1];
    sAh[s] = (const char*)Ah + ((size_t)gm * K + kshift) * 2 + kofs;
    sBh[s] = (const char*)Bh + ((size_t)(n0 + tr) * K + kshift) * 2 + kofs;
    if constexpr (SPLIT) {
      sAl[s] = (const char*)Al + ((size_t)gm * K + kshift) * 2 + kofs;
      sBl[s] = (const char*)Bl + ((size_t)(n0 + tr) * K + kshift) * 2 + kofs;
    }
  }
  char* const dstw = lds + wave * 4096;

  // fragment read bases (row-major 128B rows per region, chunk swizzle ^l7)
  const int s4 = lane >> 4, l7 = lane & 7, fr = lane & 15;
  int rowA[4], colB[4];
#pragma unroll
  for (int i = 0; i < 4; ++i) rowA[i] = (wr + i * 16 + fr) * 128;
#pragma unroll
  for (int j = 0; j < 4; ++j) colB[j] = RB + (wc + j * 16 + fr) * 128;
  const int ch[2] = {((s4) ^ l7) << 4, ((4 + s4) ^ l7) << 4};

  f32x4 acc[4][4] = {};

  const int nt_ = (KSPLIT ? (K >> 1) : K) >> 6;

  for (int t = 0; t < nt_; ++t) {
    const size_t kb = (size_t)t << 7;   // t * 64 elems * 2B
#pragma unroll
    for (int s = 0; s < 4; ++s) {
      async16(dstw + s * 1024, sAh[s] + kb);
      if constexpr (SPLIT) async16(dstw + 16384 + s * 1024, sAl[s] + kb);
      async16(dstw + RB + s * 1024, sBh[s] + kb);
      if constexpr (SPLIT) async16(dstw + RB + 16384 + s * 1024, sBl[s] + kb);
    }
    __syncthreads();   // drains vmcnt + barrier (m97 structure)
    __builtin_amdgcn_s_setprio(1);
#pragma unroll
    for (int kk = 0; kk < 2; ++kk) {
      f16x8 va[4], vb[4], va2[4], vb2[4];
#pragma unroll
      for (int i = 0; i < 4; ++i) {
        va[i] = *(const f16x8*)(lds + rowA[i] + ch[kk]);
        if constexpr (SPLIT) va2[i] = *(const f16x8*)(lds + 16384 + rowA[i] + ch[kk]);
      }
#pragma unroll
      for (int j = 0; j < 4; ++j) {
        vb[j] = *(const f16x8*)(lds + colB[j] + ch[kk]);
        if constexpr (SPLIT) vb2[j] = *(const f16x8*)(lds + 16384 + colB[j] + ch[kk]);
      }
#pragma unroll
      for (int i = 0; i < 4; ++i)
#pragma unroll
        for (int j = 0; j < 4; ++j) {
          acc[i][j] = __builtin_amdgcn_mfma_f32_16x16x32_f16(va[i], vb[j], acc[i][j], 0, 0, 0);
          if constexpr (SPLIT) {
            acc[i][j] = __builtin_amdgcn_mfma_f32_16x16x32_f16(va2[i], vb[j], acc[i][j], 0, 0, 0);
            acc[i][j] = __builtin_amdgcn_mfma_f32_16x16x32_f16(va[i], vb2[j], acc[i][j], 0, 0, 0);
          }
        }
    }
    __builtin_amdgcn_s_setprio(0);
    __syncthreads();   // protect buffer before next stage
  }

  const int cl = lane & 15, rg = lane >> 4;
  float* const po = (OUT == 3) ? (ks ? outf2 : outf) : outf;
#pragma unroll
  for (int i = 0; i < 4; ++i) {
#pragma unroll
    for (int r = 0; r < 4; ++r) {
      const int mloc = m0 + wr + i * 16 + rg * 4 + r;
      if (GATHER && mloc >= cnt) continue;
      const int orow = GATHER ? idx[mloc] : mloc;
#pragma unroll
      for (int j = 0; j < 4; ++j) {
        const int col = n0 + wc + j * 16 + cl;
        float v2 = acc[i][j][r];
        if (BIAS) v2 += bias[col];
        if (RELU) v2 = v2 > 0.f ? v2 : 0.f;
        if (RES) v2 += res[(size_t)orow * N + col];
        size_t oidx;
        if constexpr (QKV3) {
          if (col < 2048) {
            oidx = ((size_t)(col >> 10) * M + orow) * 1024 + (col & 1023);
          } else {
            const int c = col - 2048;  // head*64 + d
            oidx = (size_t)2 * M * 1024 +
                   (((size_t)(orow >> 10) * 16 + (c >> 6)) * 64 + (c & 63)) * 1024 +
                   (orow & 1023);
          }
        } else {
          oidx = (size_t)orow * N + col;
        }
        if constexpr (OUT == 0 || OUT == 3) {
          po[oidx] = v2;
        } else if constexpr (OUT == 1) {
          f16 hi = (f16)v2;
          outh[oidx] = hi;
          outl[oidx] = (f16)(v2 - (float)hi);
        } else {
          outh[oidx] = (f16)v2;
        }
      }
    }
  }
}

// ---------------- flash attention, causal, D=64, split-fp16 -----------------
__global__ __launch_bounds__(256, 3) void attn_k(
    const f16* __restrict__ qh, const f16* __restrict__ ql,
    const f16* __restrict__ kh, const f16* __restrict__ kl,
    const f16* __restrict__ vth, const f16* __restrict__ vtl,
    f16* __restrict__ oh, f16* __restrict__ ol) {
  const int qt = 15 - (blockIdx.x & 15), hd = (blockIdx.x >> 4) & 15, bb = blockIdx.x >> 8;
  const int tid = threadIdx.x, wave = tid >> 6, lane = tid & 63;
  __shared__ __align__(16) char QPs[16384], Ks[16384], Vs[16384];
  const int swz = (((lane & 7) ^ ((lane >> 3) & 7)) << 4);
  const size_t tok0 = (size_t)bb * 1024;
  const int hoff = hd * 64;
  const size_t vbase = ((size_t)(bb * 16 + hd) * 64) * 1024;  // v_t rows
  const float L2E = 1.44269504089f;

#pragma unroll
  for (int r = 0; r < 2; ++r) {
    const int chunk = wave * 2 + r;
    const int row = chunk * 8 + (lane >> 3);
    const size_t byte = (((tok0 + qt * 64 + row) * 1024 + hoff) << 1) + swz;
    async16(QPs + chunk * 1024, (const char*)qh + byte);
    async16(QPs + 8192 + chunk * 1024, (const char*)ql + byte);
  }
  __syncthreads();
  f16x8 qr_h[2], qr_l[2];
#pragma unroll
  for (int ks = 0; ks < 2; ++ks) {
    const int qrow = wave * 16 + (lane & 15);
    const int qoff = qrow * 128 + ((((ks << 2) + (lane >> 4)) ^ (qrow & 7)) << 4);
    qr_h[ks] = *(const f16x8*)(QPs + qoff);
    qr_l[ks] = *(const f16x8*)(QPs + 8192 + qoff);
  }

  f32x4 oacc[4] = {};
  float mrun[4] = {-1e30f, -1e30f, -1e30f, -1e30f};
  float lrun[4] = {};

  for (int kt = 0; kt <= qt; ++kt) {
    __syncthreads();
#pragma unroll
    for (int r = 0; r < 2; ++r) {
      const int chunk = wave * 2 + r;
      const int row = chunk * 8 + (lane >> 3);
      const size_t kbyte = (((tok0 + kt * 64 + row) * 1024 + hoff) << 1) + swz;
      async16(Ks + chunk * 1024, (const char*)kh + kbyte);
      async16(Ks + 8192 + chunk * 1024, (const char*)kl + kbyte);
      const size_t vbyte = (((vbase + (size_t)row * 1024) + kt * 64) << 1) + swz;
      async16(Vs + chunk * 1024, (const char*)vth + vbyte);
      async16(Vs + 8192 + chunk * 1024, (const char*)vtl + vbyte);
    }
    __syncthreads();

    f32x4 s[4] = {};
#pragma unroll
    for (int ks = 0; ks < 2; ++ks) {
#pragma unroll
      for (int j = 0; j < 4; ++j) {
        const int col = j * 16 + (lane & 15);
        const int koff = col * 128 + ((((ks << 2) + (lane >> 4)) ^ (col & 7)) << 4);
        f16x8 b_h = *(const f16x8*)(Ks + koff);
        f16x8 b_l = *(const f16x8*)(Ks + 8192 + koff);
        s[j] = __builtin_amdgcn_mfma_f32_16x16x32_f16(qr_h[ks], b_h, s[j], 0, 0, 0);
        s[j] = __builtin_amdgcn_mfma_f32_16x16x32_f16(qr_l[ks], b_h, s[j], 0, 0, 0);
        s[j] = __builtin_amdgcn_mfma_f32_16x16x32_f16(qr_h[ks], b_l, s[j], 0, 0, 0);
      }
    }

    const bool diag = (kt == qt);
    float pmax[4] = {-1e30f, -1e30f, -1e30f, -1e30f};
#pragma unroll
    for (int j = 0; j < 4; ++j)
#pragma unroll
      for (int r = 0; r < 4; ++r) {
        float sv = s[j][r] * 0.125f;
        if (diag) {
          const int qloc = wave * 16 + (lane >> 4) * 4 + r;
          const int kvl = j * 16 + (lane & 15);
          if (kvl > qloc) sv = -1e30f;
        }
        s[j][r] = sv;
        pmax[r] = fmaxf(pmax[r], sv);
      }
    char* pbh = QPs + wave * 2048;
    char* pbl = QPs + 8192 + wave * 2048;
#pragma unroll
    for (int r = 0; r < 4; ++r) {
#pragma unroll
      for (int mm = 1; mm < 16; mm <<= 1)
        pmax[r] = fmaxf(pmax[r], __shfl_xor(pmax[r], mm, 16));
      const float mnew = fmaxf(mrun[r], pmax[r]);
      const float al = exp2f((mrun[r] - mnew) * L2E);
      mrun[r] = mnew;
      lrun[r] *= al;
      oacc[0][r] *= al; oacc[1][r] *= al; oacc[2][r] *= al; oacc[3][r] *= al;
    }

    float psum[4] = {};
#pragma unroll
    for (int j = 0; j < 4; ++j)
#pragma unroll
      for (int r = 0; r < 4; ++r) {
        const float p = exp2f((s[j][r] - mrun[r]) * L2E);
        psum[r] += p;
        const int lr = (lane >> 4) * 4 + r;
        const int kvl = j * 16 + (lane & 15);
        const int poff = lr * 128 + ((kvl * 2) ^ ((lr & 7) << 4));
        f16 ph = (f16)p;
        *(f16*)(pbh + poff) = ph;
        *(f16*)(pbl + poff) = (f16)(p - (float)ph);
      }
#pragma unroll
    for (int r = 0; r < 4; ++r) {
#pragma unroll
      for (int mm = 1; mm < 16; mm <<= 1)
        psum[r] += __shfl_xor(psum[r], mm, 16);
      lrun[r] += psum[r];
    }

#pragma unroll
    for (int ks = 0; ks < 2; ++ks) {
      const int prow = lane & 15;
      const int poff = prow * 128 + ((((ks << 2) + (lane >> 4)) ^ (prow & 7)) << 4);
      f16x8 a_h = *(const f16x8*)(pbh + poff);
      f16x8 a_l = *(const f16x8*)(pbl + poff);
#pragma unroll
      for (int jd = 0; jd < 4; ++jd) {
        const int col = jd * 16 + (lane & 15);
        const int voff = col * 128 + ((((ks << 2) + (lane >> 4)) ^ (col & 7)) << 4);
        f16x8 b_h = *(const f16x8*)(Vs + voff);
        f16x8 b_l = *(const f16x8*)(Vs + 8192 + voff);
        oacc[jd] = __builtin_amdgcn_mfma_f32_16x16x32_f16(a_h, b_h, oacc[jd], 0, 0, 0);
        oacc[jd] = __builtin_amdgcn_mfma_f32_16x16x32_f16(a_l, b_h, oacc[jd], 0, 0, 0);
        oacc[jd] = __builtin_amdgcn_mfma_f32_16x16x32_f16(a_h, b_l, oacc[jd], 0, 0, 0);
      }
    }
  }

#pragma unroll
  for (int r = 0; r < 4; ++r) {
    const float inv = 1.0f / lrun[r];
    const size_t trow = tok0 + qt * 64 + wave * 16 + (lane >> 4) * 4 + r;
#pragma unroll
    for (int jd = 0; jd < 4; ++jd) {
      const int col = hoff + jd * 16 + (lane & 15);
      const float val = oacc[jd][r] * inv;
      const f16 hi = (f16)val;
      oh[trow * 1024 + col] = hi;
      ol[trow * 1024 + col] = (f16)(val - (float)hi);
    }
  }
}

// ---------------------------------------------------------------------------
extern "C" void kernel_launch(void* const* d_in, const int* in_sizes, int n_in,
                              void* d_out, int out_size, void* d_ws, size_t ws_size,
                              hipStream_t stream) {
  const float* x0   = (const float*)d_in[0];
  const float* wq   = (const float*)d_in[1];
  const float* wk   = (const float*)d_in[2];
  const float* wv   = (const float*)d_in[3];
  const float* wo   = (const float*)d_in[4];
  const float* bo   = (const float*)d_in[5];
  const float* ffw1 = (const float*)d_in[6];
  const float* ffb1 = (const float*)d_in[7];
  const float* ffw2 = (const float*)d_in[8];
  const float* ffb2 = (const float*)d_in[9];
  const float* ew1  = (const float*)d_in[10];
  const float* eb1  = (const float*)d_in[11];
  const float* ew2  = (const float*)d_in[12];
  const float* eb2  = (const float*)d_in[13];
  const float* gw   = (const float*)d_in[14];
  const float* gb   = (const float*)d_in[15];
  const float* l1g  = (const float*)d_in[16];
  const float* l1b  = (const float*)d_in[17];
  const float* l2g  = (const float*)d_in[18];
  const float* l2b  = (const float*)d_in[19];
  const float* l3g  = (const float*)d_in[20];
  const float* l3b  = (const float*)d_in[21];
  float* out = (float*)d_out;

  char* w = (char*)d_ws;
  const size_t M1 = (size_t)1024 * 1024;       // elems of a 1024x1024 f16
  const size_t A1 = (size_t)4096 * 1024 * 2;   // 8MB  (f16 4096x1024)
  const size_t W4 = (size_t)1024 * 4096 * 2;   // 8MB  (f16 1024x4096)
  f16* wqkvh = (f16*)w; w += 3 * M1 * 2;       // 6MB  [3072][1024] hi
  f16* wqkvl = (f16*)w; w += 3 * M1 * 2;       // 6MB  lo
  f16* woh = (f16*)w; w += M1 * 2;             // 2MB
  f16* wol = (f16*)w; w += M1 * 2;             // 2MB
  f16* f1h = (f16*)w; w += W4;  f16* f1l = (f16*)w; w += W4;
  f16* f2h = (f16*)w; w += W4;  f16* f2l = (f16*)w; w += W4;
  f16* e1t = (f16*)w; w += 4 * W4;
  f16* e2t = (f16*)w; w += 4 * W4;
  f16* hh  = (f16*)w; w += A1;  f16* hl  = (f16*)w; w += A1;
  f16* qkv_h = (f16*)w; w += 3 * A1;           // q,k row-major; v transposed
  f16* qkv_l = (f16*)w; w += 3 * A1;
  f16* o_h = (f16*)w; w += A1;  f16* o_l = (f16*)w; w += A1;
  float* x1 = (float*)w; w += (size_t)4096 * 1024 * 4;
  int* cnt = (int*)w; w += 256;
  int* idx = (int*)w; w += (size_t)4 * 4096 * 4;
  int* eid = (int*)w; w += (size_t)4096 * 4;
  int* desc = (int*)w; w += 256;
  // aliases over sequentially-dead regions:
  f16* hid_h = qkv_h;                                     // FFN hidden hi (32MB)
  f16* hid_l = (f16*)((char*)qkv_h + (((size_t)32) << 20)); // FFN hidden lo (32MB)
  f16* ffh   = qkv_h;                                     // MoE hidden (32MB)
  // K-split partial buffers (16MB each), all over dead regions at use time:
  float* pW0 = (float*)hh;      // wo: ln1-out dead after qkv
  float* pW1 = (float*)qkv_h;   // wo: q/k/v dead after attn
  float* pF0 = (float*)wqkvh;   // ff2: qkv+wo weights dead
  float* pF1 = (float*)hh;      // ff2: ln2-out dead after ff1
  float* pM0 = (float*)((char*)qkv_l + (((size_t)8) << 20));  // moe: free tail
  float* pM1 = (float*)o_h;     // moe: attn-out dead after wo

  // ---- weights -> f16 (split for pre-gate, single for experts) ----
  transpose_k<true><<<1024, 256, 0, stream>>>(wq, wqkvh, wqkvl, 1024, 1024);
  transpose_k<true><<<1024, 256, 0, stream>>>(wk, wqkvh + M1, wqkvl + M1, 1024, 1024);
  transpose_k<true><<<1024, 256, 0, stream>>>(wv, wqkvh + 2 * M1, wqkvl + 2 * M1, 1024, 1024);
  transpose_k<true><<<1024, 256, 0, stream>>>(wo, woh, wol, 1024, 1024);
  transpose_k<true><<<4096, 256, 0, stream>>>(ffw1, f1h, f1l, 1024, 4096);
  transpose_k<true><<<4096, 256, 0, stream>>>(ffw2, f2h, f2l, 4096, 1024);
  transpose_k<false><<<dim3(4096, 4), 256, 0, stream>>>(ew1, e1t, nullptr, 1024, 4096);
  transpose_k<false><<<dim3(4096, 4), 256, 0, stream>>>(ew2, e2t, nullptr, 4096, 1024);

  const size_t TOK = (size_t)4096 * 1024;
  // ---- attention ----
  ln_k<<<4096, 256, 0, stream>>>(x0, l1g, l1b, hh, hl);
  gemm_k<true, false, false, false, false, 1, true, false><<<768, 256, 0, stream>>>(
      hh, hl, wqkvh, wqkvl, nullptr, nullptr, qkv_h, qkv_l,
      nullptr, nullptr, nullptr, nullptr, nullptr, 4096, 3072, 1024);
  attn_k<<<1024, 256, 0, stream>>>(qkv_h, qkv_l, qkv_h + TOK, qkv_l + TOK,
                                   qkv_h + 2 * TOK, qkv_l + 2 * TOK, o_h, o_l);
  gemm_k<true, false, false, false, false, 3, false, true><<<512, 256, 0, stream>>>(
      o_h, o_l, woh, wol, pW0, pW1, nullptr, nullptr,
      nullptr, nullptr, nullptr, nullptr, nullptr, 4096, 1024, 1024);
  reduce_k<false><<<4096, 256, 0, stream>>>(pW0, pW1, x0, bo, nullptr, x1);

  // ---- dense FFN ----
  ln_k<<<4096, 256, 0, stream>>>(x1, l2g, l2b, hh, hl);
  gemm_k<true, true, true, false, false, 1, false, false><<<1024, 256, 0, stream>>>(
      hh, hl, f1h, f1l, nullptr, nullptr, hid_h, hid_l,
      ffb1, nullptr, nullptr, nullptr, nullptr, 4096, 4096, 1024);
  gemm_k<true, false, false, false, false, 3, false, true><<<512, 256, 0, stream>>>(
      hid_h, hid_l, f2h, f2l, pF0, pF1, nullptr, nullptr,
      nullptr, nullptr, nullptr, nullptr, nullptr, 4096, 1024, 4096);
  reduce_k<false><<<4096, 256, 0, stream>>>(pF0, pF1, x1, ffb2, nullptr, out);

  // ---- MoE (top-1 routed; gate in pure f32; dense tile plan) ----
  ln_k<<<4096, 256, 0, stream>>>(out, l3g, l3b, hh, hl);
  init_moe<<<1, 64, 0, stream>>>(cnt);
  gate_k<<<4096, 256, 0, stream>>>(out, l3g, l3b, gw, gb, cnt, idx, eid);
  plan_k<<<1, 64, 0, stream>>>(cnt, desc);
  gemm_k<false, true, true, false, true, 2, false, false><<<MAXMT * 32, 256, 0, stream>>>(
      hh, nullptr, e1t, nullptr, nullptr, nullptr, ffh, nullptr,
      eb1, nullptr, idx, cnt, desc, 4096, 4096, 1024);
  gemm_k<false, false, false, false, true, 3, false, true><<<2 * MAXMT * 8, 256, 0, stream>>>(
      ffh, nullptr, e2t, nullptr, pM0, pM1, nullptr, nullptr,
      nullptr, nullptr, idx, cnt, desc, 4096, 1024, 4096);
  reduce_k<true><<<4096, 256, 0, stream>>>(pM0, pM1, out, eb2, eid, out);
}